// Round 13
// baseline (317.301 us; speedup 1.0000x reference)
//
#include <hip/hip_runtime.h>
#include <stdint.h>

// Problem constants (fixed by reference setup_inputs)
#define NTOK   8192
#define NEXP   64
#define HID    4096
#define TOPK   8
#define OUTROW 65536   // NTOK * TOPK
#define CHUNK  256     // tokens per chunk
#define NCHUNK 32      // NTOK / CHUNK
#define NPART  2048    // NEXP * NCHUNK, expert-major chunk-minor

typedef float f32x4 __attribute__((ext_vector_type(4)));
typedef unsigned long long u64;

// ---------------------------------------------------------------------------
// K1: per-token expert bitmasks + per-(expert,chunk) counts.
// 32 blocks x 256 threads (one block per token chunk); map read exactly once
// (coalesced: lane = expert).
__global__ void mask_count_kernel(const int* __restrict__ map,
                                  u64* __restrict__ masks,
                                  int* __restrict__ pcnt) {
    int c = blockIdx.x;
    int tid = threadIdx.x;
    int w = tid >> 6, lane = tid & 63;

    __shared__ u64 sm[CHUNK];
    __shared__ int hcnt[NEXP];
    if (tid < NEXP) hcnt[tid] = 0;

    int t0 = c * CHUNK + w * 64;
#pragma unroll 8
    for (int i = 0; i < 64; ++i) {
        int v = map[(size_t)(t0 + i) * NEXP + lane];   // coalesced: lane = expert
        u64 bal = __ballot(v != 0);
        if (lane == 0) sm[w * 64 + i] = bal;
    }
    __syncthreads();

    u64 mk = sm[tid];
    masks[c * CHUNK + tid] = mk;                       // global token id = c*256+tid
    while (mk) {
        int e = __ffsll((long long)mk) - 1;
        atomicAdd(&hcnt[e], 1);
        mk &= mk - 1;
    }
    __syncthreads();
    if (tid < NEXP) pcnt[tid * NCHUNK + c] = hcnt[tid]; // flat [e][c] layout
}

// ---------------------------------------------------------------------------
// K2: exclusive prefix over the 2048 flat (expert-major, chunk-minor) counts.
__global__ void scan_kernel(const int* __restrict__ pcnt, int* __restrict__ poffs) {
    __shared__ int s[256];
    int tid = threadIdx.x;
    int v[8];
    int sum = 0;
#pragma unroll
    for (int i = 0; i < 8; ++i) { v[i] = pcnt[tid * 8 + i]; sum += v[i]; }
    s[tid] = sum;
    __syncthreads();
    for (int off = 1; off < 256; off <<= 1) {
        int x = (tid >= off) ? s[tid - off] : 0;
        __syncthreads();
        s[tid] += x;
        __syncthreads();
    }
    int base = (tid == 0) ? 0 : s[tid - 1];  // exclusive
#pragma unroll
    for (int i = 0; i < 8; ++i) { poffs[tid * 8 + i] = base; base += v[i]; }
}

// ---------------------------------------------------------------------------
// K3 (segment): destination-major. One block per (chunk, expert), blockIdx =
// c*64+e so the whole grid (2048 blocks, fully co-resident) reads only the
// 134 MB token array (LLC-resident; plain cached loads) while each block
// WRITES A SINGLE CONTIGUOUS ~512 KB segment (same write shape as the
// 6.6 TB/s fill kernels; nt stores -> no MALL allocation, token lines stay).
// Row list + ranks from one ballot over the chunk's masks; probs/idx written
// by the owning thread. 2-row unrolled copy loop for MLP.
__global__ void seg_kernel(const u64* __restrict__ masks,
                           const float* __restrict__ probs,
                           const int* __restrict__ poffs,
                           const float* __restrict__ tokens,
                           float* __restrict__ out_rows,
                           float* __restrict__ out_probs,
                           float* __restrict__ out_idx) {
    int blk = blockIdx.x;
    int c = blk >> 6, e = blk & 63;
    int tid = threadIdx.x;
    int w = tid >> 6, lane = tid & 63;

    __shared__ int s_src[CHUNK];
    __shared__ int wcnt[4];

    int t = c * CHUNK + tid;
    u64 mk = masks[t];                                  // coalesced 8B
    bool m = (mk >> e) & 1ull;
    u64 bal = __ballot(m);
    int rank = __popcll(bal & ((1ull << lane) - 1ull));
    if (lane == 0) wcnt[w] = __popcll(bal);
    __syncthreads();
    int wbase = 0;
#pragma unroll
    for (int i = 0; i < 4; ++i) wbase += (i < w) ? wcnt[i] : 0;
    int total = wcnt[0] + wcnt[1] + wcnt[2] + wcnt[3];
    int base = poffs[e * NCHUNK + c];

    if (m) {
        int local = wbase + rank;
        s_src[local] = t;
        int pos = base + local;
        out_idx[pos] = (float)t;                        // exact for t < 2^24
        out_probs[pos] = probs[(size_t)t * NEXP + e];
    }
    __syncthreads();

    // contiguous segment copy: rows [base, base+total), 2-row unroll
    int i = 0;
    for (; i + 2 <= total; i += 2) {
        int s0 = s_src[i], s1 = s_src[i + 1];
        const f32x4* sp0 = (const f32x4*)(tokens + (size_t)s0 * HID);
        const f32x4* sp1 = (const f32x4*)(tokens + (size_t)s1 * HID);
        f32x4* dp0 = (f32x4*)(out_rows + (size_t)(base + i) * HID);
        f32x4* dp1 = (f32x4*)(out_rows + (size_t)(base + i + 1) * HID);
        f32x4 a0 = sp0[tid], a1 = sp0[tid + 256], a2 = sp0[tid + 512], a3 = sp0[tid + 768];
        f32x4 b0 = sp1[tid], b1 = sp1[tid + 256], b2 = sp1[tid + 512], b3 = sp1[tid + 768];
        __builtin_nontemporal_store(a0, dp0 + tid);
        __builtin_nontemporal_store(a1, dp0 + tid + 256);
        __builtin_nontemporal_store(a2, dp0 + tid + 512);
        __builtin_nontemporal_store(a3, dp0 + tid + 768);
        __builtin_nontemporal_store(b0, dp1 + tid);
        __builtin_nontemporal_store(b1, dp1 + tid + 256);
        __builtin_nontemporal_store(b2, dp1 + tid + 512);
        __builtin_nontemporal_store(b3, dp1 + tid + 768);
    }
    if (i < total) {
        int s0 = s_src[i];
        const f32x4* sp0 = (const f32x4*)(tokens + (size_t)s0 * HID);
        f32x4* dp0 = (f32x4*)(out_rows + (size_t)(base + i) * HID);
        f32x4 a0 = sp0[tid], a1 = sp0[tid + 256], a2 = sp0[tid + 512], a3 = sp0[tid + 768];
        __builtin_nontemporal_store(a0, dp0 + tid);
        __builtin_nontemporal_store(a1, dp0 + tid + 256);
        __builtin_nontemporal_store(a2, dp0 + tid + 512);
        __builtin_nontemporal_store(a3, dp0 + tid + 768);
    }
}

// ---------------------------------------------------------------------------
extern "C" void kernel_launch(void* const* d_in, const int* in_sizes, int n_in,
                              void* d_out, int out_size, void* d_ws, size_t ws_size,
                              hipStream_t stream) {
    const float* tokens = (const float*)d_in[0];
    const float* probs  = (const float*)d_in[1];
    const int*   map    = (const int*)d_in[2];

    float* out_rows  = (float*)d_out;                    // [OUTROW, HID]
    float* out_probs = out_rows + (size_t)OUTROW * HID;  // [OUTROW]
    float* out_idx   = out_probs + OUTROW;               // [OUTROW] float-coded ids

    // workspace: masks 64KB + pcnt 8KB + poffs 8KB
    u64* masks = (u64*)d_ws;
    int* pcnt  = (int*)(masks + NTOK);
    int* poffs = pcnt + NPART;

    mask_count_kernel<<<NCHUNK, CHUNK, 0, stream>>>(map, masks, pcnt);
    scan_kernel<<<1, CHUNK, 0, stream>>>(pcnt, poffs);
    seg_kernel<<<NPART, CHUNK, 0, stream>>>(masks, probs, poffs, tokens,
                                            out_rows, out_probs, out_idx);
}

// Round 14
// 242.056 us; speedup vs baseline: 1.3109x; 1.3109x over previous
//
#include <hip/hip_runtime.h>
#include <stdint.h>

// Problem constants (fixed by reference setup_inputs)
#define NTOK   8192
#define NEXP   64
#define HID    4096
#define TOPK   8
#define OUTROW 65536   // NTOK * TOPK
#define CHUNK  256     // tokens per chunk
#define NCHUNK 32      // NTOK / CHUNK
#define NPART  2048    // NEXP * NCHUNK, expert-major chunk-minor

typedef float f32x4 __attribute__((ext_vector_type(4)));
typedef unsigned long long u64;

// ---------------------------------------------------------------------------
// K1: per-token expert bitmasks + per-(expert,chunk) counts.
// 32 blocks x 256 threads (one block per token chunk); map read exactly once
// (coalesced: lane = expert).
__global__ void mask_count_kernel(const int* __restrict__ map,
                                  u64* __restrict__ masks,
                                  int* __restrict__ pcnt) {
    int c = blockIdx.x;
    int tid = threadIdx.x;
    int w = tid >> 6, lane = tid & 63;

    __shared__ u64 sm[CHUNK];
    __shared__ int hcnt[NEXP];
    if (tid < NEXP) hcnt[tid] = 0;

    int t0 = c * CHUNK + w * 64;
#pragma unroll 8
    for (int i = 0; i < 64; ++i) {
        int v = map[(size_t)(t0 + i) * NEXP + lane];   // coalesced: lane = expert
        u64 bal = __ballot(v != 0);
        if (lane == 0) sm[w * 64 + i] = bal;
    }
    __syncthreads();

    u64 mk = sm[tid];
    masks[c * CHUNK + tid] = mk;                       // global token id = c*256+tid
    while (mk) {
        int e = __ffsll((long long)mk) - 1;
        atomicAdd(&hcnt[e], 1);
        mk &= mk - 1;
    }
    __syncthreads();
    if (tid < NEXP) pcnt[tid * NCHUNK + c] = hcnt[tid]; // flat [e][c] layout
}

// ---------------------------------------------------------------------------
// K2: exclusive prefix over the 2048 flat (expert-major, chunk-minor) counts.
__global__ void scan_kernel(const int* __restrict__ pcnt, int* __restrict__ poffs) {
    __shared__ int s[256];
    int tid = threadIdx.x;
    int v[8];
    int sum = 0;
#pragma unroll
    for (int i = 0; i < 8; ++i) { v[i] = pcnt[tid * 8 + i]; sum += v[i]; }
    s[tid] = sum;
    __syncthreads();
    for (int off = 1; off < 256; off <<= 1) {
        int x = (tid >= off) ? s[tid - off] : 0;
        __syncthreads();
        s[tid] += x;
        __syncthreads();
    }
    int base = (tid == 0) ? 0 : s[tid - 1];  // exclusive
#pragma unroll
    for (int i = 0; i < 8; ++i) { poffs[tid * 8 + i] = base; base += v[i]; }
}

// ---------------------------------------------------------------------------
// K3 (segment, XCD-swizzled): destination-major with L2 locality. SINGLE
// change vs R13: blockIdx remap so all 64 expert-blocks of one chunk land on
// the SAME XCD (bid%8 round-robin heuristic; speed-only, never correctness).
//   xcd = bid & 7; i = bid >> 3; c = xcd + 8*(i>>6); e = i & 63
// Each XCD then works 4 chunks in temporal phases; the chunk's 4 MB token
// slice is L2-resident so the 7x logical re-reads are L2 hits instead of
// cross-die LLC/HBM traffic. Writes unchanged: one contiguous ~512 KB nt
// segment per block (the 6.6 TB/s fill shape).
__global__ void seg_kernel(const u64* __restrict__ masks,
                           const float* __restrict__ probs,
                           const int* __restrict__ poffs,
                           const float* __restrict__ tokens,
                           float* __restrict__ out_rows,
                           float* __restrict__ out_probs,
                           float* __restrict__ out_idx) {
    int bid = blockIdx.x;
    int xcd = bid & 7;
    int i4  = bid >> 3;                  // 0..255 within XCD
    int c = xcd + 8 * (i4 >> 6);         // chunk: all 64 e-blocks share XCD
    int e = i4 & 63;
    int tid = threadIdx.x;
    int w = tid >> 6, lane = tid & 63;

    __shared__ int s_src[CHUNK];
    __shared__ int wcnt[4];

    int t = c * CHUNK + tid;
    u64 mk = masks[t];                                  // coalesced 8B
    bool m = (mk >> e) & 1ull;
    u64 bal = __ballot(m);
    int rank = __popcll(bal & ((1ull << lane) - 1ull));
    if (lane == 0) wcnt[w] = __popcll(bal);
    __syncthreads();
    int wbase = 0;
#pragma unroll
    for (int i = 0; i < 4; ++i) wbase += (i < w) ? wcnt[i] : 0;
    int total = wcnt[0] + wcnt[1] + wcnt[2] + wcnt[3];
    int base = poffs[e * NCHUNK + c];

    if (m) {
        int local = wbase + rank;
        s_src[local] = t;
        int pos = base + local;
        out_idx[pos] = (float)t;                        // exact for t < 2^24
        out_probs[pos] = probs[(size_t)t * NEXP + e];
    }
    __syncthreads();

    // contiguous segment copy: rows [base, base+total), 2-row unroll
    int i = 0;
    for (; i + 2 <= total; i += 2) {
        int s0 = s_src[i], s1 = s_src[i + 1];
        const f32x4* sp0 = (const f32x4*)(tokens + (size_t)s0 * HID);
        const f32x4* sp1 = (const f32x4*)(tokens + (size_t)s1 * HID);
        f32x4* dp0 = (f32x4*)(out_rows + (size_t)(base + i) * HID);
        f32x4* dp1 = (f32x4*)(out_rows + (size_t)(base + i + 1) * HID);
        f32x4 a0 = sp0[tid], a1 = sp0[tid + 256], a2 = sp0[tid + 512], a3 = sp0[tid + 768];
        f32x4 b0 = sp1[tid], b1 = sp1[tid + 256], b2 = sp1[tid + 512], b3 = sp1[tid + 768];
        __builtin_nontemporal_store(a0, dp0 + tid);
        __builtin_nontemporal_store(a1, dp0 + tid + 256);
        __builtin_nontemporal_store(a2, dp0 + tid + 512);
        __builtin_nontemporal_store(a3, dp0 + tid + 768);
        __builtin_nontemporal_store(b0, dp1 + tid);
        __builtin_nontemporal_store(b1, dp1 + tid + 256);
        __builtin_nontemporal_store(b2, dp1 + tid + 512);
        __builtin_nontemporal_store(b3, dp1 + tid + 768);
    }
    if (i < total) {
        int s0 = s_src[i];
        const f32x4* sp0 = (const f32x4*)(tokens + (size_t)s0 * HID);
        f32x4* dp0 = (f32x4*)(out_rows + (size_t)(base + i) * HID);
        f32x4 a0 = sp0[tid], a1 = sp0[tid + 256], a2 = sp0[tid + 512], a3 = sp0[tid + 768];
        __builtin_nontemporal_store(a0, dp0 + tid);
        __builtin_nontemporal_store(a1, dp0 + tid + 256);
        __builtin_nontemporal_store(a2, dp0 + tid + 512);
        __builtin_nontemporal_store(a3, dp0 + tid + 768);
    }
}

// ---------------------------------------------------------------------------
extern "C" void kernel_launch(void* const* d_in, const int* in_sizes, int n_in,
                              void* d_out, int out_size, void* d_ws, size_t ws_size,
                              hipStream_t stream) {
    const float* tokens = (const float*)d_in[0];
    const float* probs  = (const float*)d_in[1];
    const int*   map    = (const int*)d_in[2];

    float* out_rows  = (float*)d_out;                    // [OUTROW, HID]
    float* out_probs = out_rows + (size_t)OUTROW * HID;  // [OUTROW]
    float* out_idx   = out_probs + OUTROW;               // [OUTROW] float-coded ids

    // workspace: masks 64KB + pcnt 8KB + poffs 8KB
    u64* masks = (u64*)d_ws;
    int* pcnt  = (int*)(masks + NTOK);
    int* poffs = pcnt + NPART;

    mask_count_kernel<<<NCHUNK, CHUNK, 0, stream>>>(map, masks, pcnt);
    scan_kernel<<<1, CHUNK, 0, stream>>>(pcnt, poffs);
    seg_kernel<<<NPART, CHUNK, 0, stream>>>(masks, probs, poffs, tokens,
                                            out_rows, out_probs, out_idx);
}

// Round 15
// 240.530 us; speedup vs baseline: 1.3192x; 1.0063x over previous
//
#include <hip/hip_runtime.h>
#include <stdint.h>

// Problem constants (fixed by reference setup_inputs)
#define NTOK   8192
#define NEXP   64
#define HID    4096
#define TOPK   8
#define OUTROW 65536   // NTOK * TOPK
#define CHUNK  256     // tokens per chunk
#define NCHUNK 32      // NTOK / CHUNK
#define NPART  2048    // NEXP * NCHUNK
#define LISTSZ (CHUNK * TOPK)   // 2048 entries per chunk (exactly, TOPK fixed)
#define RPB    32      // rows per seg block = LISTSZ / 64

typedef float f32x4 __attribute__((ext_vector_type(4)));
typedef unsigned long long u64;

// pack (token 13b | expert 6b | rank 8b) into u32
#define PACK(t, e, r) (((unsigned)(t) << 14) | ((unsigned)(e) << 8) | (unsigned)(r))

// ---------------------------------------------------------------------------
// K1: masks -> per-token ranks -> per-chunk flat work list (output order) +
// per-(expert,chunk) counts. 32 blocks x 256 threads; map read exactly once
// (coalesced: lane = expert).
__global__ void mask_list_kernel(const int* __restrict__ map,
                                 unsigned* __restrict__ chunk_list,
                                 int* __restrict__ pcnt) {
    int c = blockIdx.x;
    int tid = threadIdx.x;
    int w = tid >> 6, lane = tid & 63;

    __shared__ u64 sm[CHUNK];                   // 2 KB
    __shared__ unsigned short rnk[CHUNK][NEXP]; // 32 KB
    __shared__ int wtot[4][NEXP];               // 1 KB
    __shared__ int pref[NEXP];                  // 256 B
    __shared__ unsigned s_list[LISTSZ];         // 8 KB

    // build masks via ballot (lane = expert; coalesced 256B rows)
    int t0 = c * CHUNK + w * 64;
#pragma unroll 8
    for (int i = 0; i < 64; ++i) {
        int v = map[(size_t)(t0 + i) * NEXP + lane];
        u64 bal = __ballot(v != 0);
        if (lane == 0) sm[w * 64 + i] = bal;
    }
    __syncthreads();

    // exclusive running count per expert over this wave's 64 tokens
    int cnt = 0;
#pragma unroll 8
    for (int i = 0; i < 64; ++i) {
        u64 mk = sm[w * 64 + i];                // broadcast LDS read
        rnk[w * 64 + i][lane] = (unsigned short)cnt;
        cnt += (int)((mk >> lane) & 1ull);
    }
    wtot[w][lane] = cnt;
    __syncthreads();

    // chunk-local exclusive prefix over experts (trivial serial: 64 adds)
    if (tid == 0) {
        int acc = 0;
        for (int e = 0; e < NEXP; ++e) {
            pref[e] = acc;
            acc += wtot[0][e] + wtot[1][e] + wtot[2][e] + wtot[3][e];
        }
    }
    __syncthreads();

    // per-token: scatter its 8 entries into the chunk-local flat list.
    // flatk = pref[e] + rank is a bijection onto [0, 2048) (exactly 8 set
    // bits per token), so s_list is fully written.
    u64 mk = sm[tid];
    int t = c * CHUNK + tid;
    u64 tmp = mk;
#pragma unroll
    for (int j = 0; j < TOPK; ++j) {
        int e = tmp ? (__ffsll((long long)tmp) - 1) : 0;  // defensive
        tmp &= tmp - 1;
        int r = rnk[tid][e];
        if (w > 0) r += wtot[0][e];
        if (w > 1) r += wtot[1][e];
        if (w > 2) r += wtot[2][e];
        int flatk = pref[e] + r;
        s_list[flatk & (LISTSZ - 1)] = PACK(t, e, r);
    }
    __syncthreads();

    // linear coalesced write of the list + per-chunk expert counts
#pragma unroll
    for (int i = 0; i < TOPK; ++i)
        chunk_list[c * LISTSZ + i * CHUNK + tid] = s_list[i * CHUNK + tid];
    if (tid < NEXP)
        pcnt[tid * NCHUNK + c] = wtot[0][tid] + wtot[1][tid] + wtot[2][tid] + wtot[3][tid];
}

// ---------------------------------------------------------------------------
// K2: exclusive prefix over the 2048 flat (expert-major, chunk-minor) counts.
__global__ void scan_kernel(const int* __restrict__ pcnt, int* __restrict__ poffs) {
    __shared__ int s[256];
    int tid = threadIdx.x;
    int v[8];
    int sum = 0;
#pragma unroll
    for (int i = 0; i < 8; ++i) { v[i] = pcnt[tid * 8 + i]; sum += v[i]; }
    s[tid] = sum;
    __syncthreads();
    for (int off = 1; off < 256; off <<= 1) {
        int x = (tid >= off) ? s[tid - off] : 0;
        __syncthreads();
        s[tid] += x;
        __syncthreads();
    }
    int base = (tid == 0) ? 0 : s[tid - 1];  // exclusive
#pragma unroll
    for (int i = 0; i < 8; ++i) { poffs[tid * 8 + i] = base; base += v[i]; }
}

// ---------------------------------------------------------------------------
// K3 (seg, balanced): 2048 blocks, 64 per chunk, each copies EXACTLY 32 rows
// from the chunk's precomputed work list — zero imbalance, zero ballot
// prelude. XCD swizzle (R14's win, +25 us): all 64 blocks of a chunk land on
// one XCD -> the chunk's 4 MB token slice is L2-resident; logical re-reads
// are L2 hits. Plain (cached) token loads + nt stores (no MALL/L2 pollution
// by the 1.07 GB write stream). dst positions are contiguous runs (list is
// in output order).
__global__ void seg_kernel(const unsigned* __restrict__ chunk_list,
                           const float* __restrict__ probs,
                           const int* __restrict__ poffs,
                           const float* __restrict__ tokens,
                           float* __restrict__ out_rows,
                           float* __restrict__ out_probs,
                           float* __restrict__ out_idx) {
    int bid = blockIdx.x;
    int xcd = bid & 7;
    int i4  = bid >> 3;                  // 0..255 within XCD
    int c = xcd + 8 * (i4 >> 6);         // chunk: all 64 sub-blocks share XCD
    int j = i4 & 63;                     // sub-block: flat entries [j*32, j*32+32)
    int tid = threadIdx.x;

    __shared__ int s_src[RPB];
    __shared__ int s_dst[RPB];

    if (tid < RPB) {
        unsigned ent = chunk_list[c * LISTSZ + j * RPB + tid];
        int t = ent >> 14;
        int e = (ent >> 8) & 63;
        int r = ent & 255;
        int pos = poffs[e * NCHUNK + c] + r;
        if ((unsigned)pos >= OUTROW) pos = 0;            // defensive: never fault
        s_src[tid] = t;
        s_dst[tid] = pos;
        out_idx[pos] = (float)t;                         // exact for t < 2^24
        out_probs[pos] = probs[(size_t)t * NEXP + e];
    }
    __syncthreads();

    // 32 rows, 2-row unrolled copy (plain cached loads, nt stores)
    for (int i = 0; i < RPB; i += 2) {
        int s0 = s_src[i], s1 = s_src[i + 1];
        const f32x4* sp0 = (const f32x4*)(tokens + (size_t)s0 * HID);
        const f32x4* sp1 = (const f32x4*)(tokens + (size_t)s1 * HID);
        f32x4* dp0 = (f32x4*)(out_rows + (size_t)s_dst[i] * HID);
        f32x4* dp1 = (f32x4*)(out_rows + (size_t)s_dst[i + 1] * HID);
        f32x4 a0 = sp0[tid], a1 = sp0[tid + 256], a2 = sp0[tid + 512], a3 = sp0[tid + 768];
        f32x4 b0 = sp1[tid], b1 = sp1[tid + 256], b2 = sp1[tid + 512], b3 = sp1[tid + 768];
        __builtin_nontemporal_store(a0, dp0 + tid);
        __builtin_nontemporal_store(a1, dp0 + tid + 256);
        __builtin_nontemporal_store(a2, dp0 + tid + 512);
        __builtin_nontemporal_store(a3, dp0 + tid + 768);
        __builtin_nontemporal_store(b0, dp1 + tid);
        __builtin_nontemporal_store(b1, dp1 + tid + 256);
        __builtin_nontemporal_store(b2, dp1 + tid + 512);
        __builtin_nontemporal_store(b3, dp1 + tid + 768);
    }
}

// ---------------------------------------------------------------------------
extern "C" void kernel_launch(void* const* d_in, const int* in_sizes, int n_in,
                              void* d_out, int out_size, void* d_ws, size_t ws_size,
                              hipStream_t stream) {
    const float* tokens = (const float*)d_in[0];
    const float* probs  = (const float*)d_in[1];
    const int*   map    = (const int*)d_in[2];

    float* out_rows  = (float*)d_out;                    // [OUTROW, HID]
    float* out_probs = out_rows + (size_t)OUTROW * HID;  // [OUTROW]
    float* out_idx   = out_probs + OUTROW;               // [OUTROW] float-coded ids

    // workspace: chunk_list 256KB + pcnt 8KB + poffs 8KB
    unsigned* chunk_list = (unsigned*)d_ws;
    int* pcnt  = (int*)(chunk_list + NTOK * TOPK);
    int* poffs = pcnt + NPART;

    mask_list_kernel<<<NCHUNK, CHUNK, 0, stream>>>(map, chunk_list, pcnt);
    scan_kernel<<<1, CHUNK, 0, stream>>>(pcnt, poffs);
    seg_kernel<<<NPART, CHUNK, 0, stream>>>(chunk_list, probs, poffs, tokens,
                                            out_rows, out_probs, out_idx);
}